// Round 6
// baseline (134.585 us; speedup 1.0000x reference)
//
#include <hip/hip_runtime.h>
#include <math.h>

#define S_LEN  4096
#define NCH    64
#define TILE_S 64
#define RPT    8           // s-rows per thread
#define TY     8           // 512 threads = 8 waves
#define NQ     32          // staged quads (128 rows = 64 tile + 64 halo)
#define NQS    33          // padded quad stride per channel (132 dw; 132%32=4 -> balanced)
#define WQ     18          // window quads per thread (72 rows >= 69 needed)
#define WLEN   72          // win floats; used indices 1..69

// ---------------------------------------------------------------------------
// Round-9. R5 NULL (RPT=16 = RPT=8) -> amortization exhausted. Archive clue:
// R2/R3 VGPR_Count=40, but a live sliding window needs ~20 win + 24 acc +
// addr >> 40. Conclusion: the compiler SINKS each window ds_read to its first
// FMA use (hence tiny live set), defeating the source-level prefetch distance
// -> ~120cy LDS latency exposed ~18x per tile, correlated across the block's
// 8 waves (they leave the barrier together) -> occupancy can't hide it
// (R1-null) and VALUBusy sits ~34% (R2/R4). This explains why bulk-sync,
// ring, b32->b128, and RPT all nulled: none touched load sinking.
// Fix: ONE burst of all 18 ds_read_b128, then __builtin_amdgcn_sched_barrier(0)
// to pin the boundary (nothing crosses), then 848 pure-VALU literal-weight
// FMAs. 18 exposed stalls/tile -> 1 drain (~340cy, progressively lgkm-waited).
// Cost: window fully live -> ~110 VGPR -> launch_bounds(512,4), 4 waves/SIMD
// (fine: R1 proved wave count isn't the lever; stall count is).
// Kept: constexpr literal weights (R4 win), transposed quad LDS, XCD swizzle.
// ---------------------------------------------------------------------------

// ---- constexpr weight construction (compile-time) --------------------------
constexpr double cexp_(double v) {            // v in [-25, 0]
  const double LN2 = 0.6931471805599453;
  double t = v / LN2;
  int k = (int)t;
  if (t < 0.0 && (double)k != t) --k;
  double r = v - (double)k * LN2;             // r in [0, ln2)
  double term = 1.0, sum = 1.0;
  for (int n = 1; n <= 22; ++n) { term *= r / (double)n; sum += term; }
  while (k > 0) { sum *= 2.0; --k; }
  while (k < 0) { sum *= 0.5; ++k; }
  return sum;
}
constexpr double csqrt_(double a) {
  double y = a > 1.0 ? a : 1.0;
  for (int i = 0; i < 64; ++i) y = 0.5 * (y + a / y);
  return y;
}
struct Wt { float w6[62]; float w3[32]; float w1[12]; };
constexpr Wt make_weights() {
  Wt w{};
  double ip[1024] = {};
  const double delta = 10.0 / 1023.0;
  const double step  = (-5.0 + delta) + 5.0;        // == numpy x[1]-x[0]
  const double cn    = csqrt_(csqrt_(1.5707963267948966)); // (pi/2)^0.25
  double s = 0.0;
  for (int i = 0; i < 1024; ++i) {
    const double xi  = (i == 1023) ? 5.0 : ((double)i * delta - 5.0);
    const double psi = (-2.0 * xi) * cexp_(-(xi * xi)) / cn;
    s += psi;
    ip[i] = s * step;
  }
  const int as_[3] = {6, 3, 1};
  const int lf_[3] = {61, 31, 11};
  for (int si = 0; si < 3; ++si) {
    const double denom = (double)as_[si] * step;
    const float  sqa   = (float)csqrt_((double)as_[si]);
    const int    lf    = lf_[si];
    for (int t = 0; t <= lf; ++t) {
      float km1 = 0.f, kt = 0.f;
      if (t >= 1)      km1 = (float)ip[(long)(((double)(t - 1)) / denom)];
      if (t <= lf - 1) kt  = (float)ip[(long)(((double)t) / denom)];
      const float val = -sqa * (km1 - kt);
      if (si == 0) w.w6[t] = val; else if (si == 1) w.w3[t] = val; else w.w1[t] = val;
    }
  }
  return w;
}
constexpr Wt CW = make_weights();
// Template variables force compile-time folding -> inline literal operands.
template <int T> constexpr float W6 = CW.w6[T];
template <int T> constexpr float W3 = CW.w3[T];
template <int T> constexpr float W1 = CW.w1[T];

// ---- compute recursion (all indices compile-time) --------------------------
template <int T, int R>
struct FmaR {
  static __device__ __forceinline__ void run(const float (&win)[WLEN],
                                             float (&a6)[RPT], float (&a3)[RPT],
                                             float (&a1)[RPT]) {
    a6[R] = fmaf(W6<T>, win[T + R + 1], a6[R]);
    if constexpr (T >= 15 && T <= 46) a3[R] = fmaf(W3<T - 15>, win[T + R + 1], a3[R]);
    if constexpr (T >= 25 && T <= 36) a1[R] = fmaf(W1<T - 25>, win[T + R + 1], a1[R]);
    FmaR<T, R + 1>::run(win, a6, a3, a1);
  }
};
template <int T>
struct FmaR<T, RPT> {
  static __device__ __forceinline__ void run(const float (&)[WLEN],
                                             float (&)[RPT], float (&)[RPT], float (&)[RPT]) {}
};

// Load quad Q of this thread's window from the transposed LDS tile.
template <int Q>
static __device__ __forceinline__ void load_quad(const float* __restrict__ colbase, int q0,
                                                 float (&win)[WLEN]) {
  const float4 v = *(const float4*)(colbase + ((q0 + Q) << 2));
  win[4 * Q + 0] = v.x; win[4 * Q + 1] = v.y; win[4 * Q + 2] = v.z; win[4 * Q + 3] = v.w;
}

// Burst: ALL 18 quads, back-to-back ds_read_b128.
template <int Q>
struct Burst {
  static __device__ __forceinline__ void run(const float* __restrict__ colbase, int q0,
                                             float (&win)[WLEN]) {
    load_quad<Q>(colbase, q0, win);
    Burst<Q + 1>::run(colbase, q0, win);
  }
};
template <>
struct Burst<WQ> {
  static __device__ __forceinline__ void run(const float* __restrict__, int, float (&)[WLEN]) {}
};

// Pure-VALU tap recursion: NO memory ops inside.
template <int T>
struct Step {
  static __device__ __forceinline__ void run(float (&win)[WLEN], float (&a6)[RPT],
                                             float (&a3)[RPT], float (&a1)[RPT]) {
    FmaR<T, 0>::run(win, a6, a3, a1);
    Step<T + 1>::run(win, a6, a3, a1);
  }
};
template <>
struct Step<62> {
  static __device__ __forceinline__ void run(float (&)[WLEN], float (&)[RPT],
                                             float (&)[RPT], float (&)[RPT]) {}
};

template <int R>
struct Store {
  static __device__ __forceinline__ void run(float* __restrict__ o1, float* __restrict__ o3,
                                             float* __restrict__ o6, const float (&a6)[RPT],
                                             const float (&a3)[RPT], const float (&a1)[RPT]) {
    o1[(size_t)R * NCH] = a1[R];
    o3[(size_t)R * NCH] = a3[R];
    o6[(size_t)R * NCH] = a6[R];
    Store<R + 1>::run(o1, o3, o6, a6, a3, a1);
  }
};
template <>
struct Store<RPT> {
  static __device__ __forceinline__ void run(float* __restrict__, float* __restrict__,
                                             float* __restrict__, const float (&)[RPT],
                                             const float (&)[RPT], const float (&)[RPT]) {}
};

template <int R>
struct Zero {
  static __device__ __forceinline__ void run(float (&a6)[RPT], float (&a3)[RPT], float (&a1)[RPT]) {
    a6[R] = 0.f; a3[R] = 0.f; a1[R] = 0.f;
    Zero<R + 1>::run(a6, a3, a1);
  }
};
template <>
struct Zero<RPT> {
  static __device__ __forceinline__ void run(float (&)[RPT], float (&)[RPT], float (&)[RPT]) {}
};

__global__ __launch_bounds__(512, 4)
void cwt_main(const float* __restrict__ x, float* __restrict__ out) {
  // transposed tile: channel-major, 33-quad padded stride, 32 staged quads
  __shared__ __align__(16) float lds[NCH * NQS * 4];   // 33792 B

  const int c  = threadIdx.x;         // 0..63 (lane = channel)
  const int ty = threadIdx.y;         // 0..7 (wave)

  // Bijective XCD swizzle (2048 % 8 == 0): 256 consecutive logical blocks per
  // XCD; consecutive sx tiles share 64 halo rows -> same-XCD L2 hits.
  const int hw = blockIdx.x;                  // 0..2047
  const int wg = ((hw & 7) << 8) + (hw >> 3);
  const int sx = wg & 63;                     // 64 s-tiles (fastest within XCD)
  const int b  = wg >> 6;                     // 32 signals
  const int s0 = sx * TILE_S;
  const int ROW0 = s0 - 32;                   // staged rows (quad-aligned halo)

  const float* __restrict__ xb = x + (size_t)b * S_LEN * NCH;

  // ---- stage 128 rows, transposed: lane=channel scalar loads (256B/wave,
  // coalesced), wave-uniform guards, then 4 ds_write_b128 per thread.
  {
    float pg[4][4];
    #pragma unroll
    for (int k = 0; k < 4; ++k) {
      #pragma unroll
      for (int j = 0; j < 4; ++j) {
        const int row = ROW0 + 16 * ty + 4 * k + j;   // wave-uniform
        float v = 0.f;
        if ((unsigned)row < (unsigned)S_LEN) v = xb[(size_t)row * NCH + c];
        pg[k][j] = v;
      }
    }
    #pragma unroll
    for (int k = 0; k < 4; ++k) {
      const int q = 4 * ty + k;
      *(float4*)&lds[c * (NQS * 4) + (q << 2)] =
          make_float4(pg[k][0], pg[k][1], pg[k][2], pg[k][3]);
    }
  }
  __syncthreads();

  // ---- burst-load the FULL window (18 ds_read_b128), fence, pure-VALU taps
  const float* __restrict__ colbase = &lds[c * (NQS * 4)];
  const int q0 = 2 * ty;                      // thread's window start quad

  float win[WLEN];
  float a6[RPT], a3[RPT], a1[RPT];
  Zero<0>::run(a6, a3, a1);
  Burst<0>::run(colbase, q0, win);            // quads 0..17, back-to-back
  __builtin_amdgcn_sched_barrier(0);          // NOTHING crosses: loads stay up
  Step<0>::run(win, a6, a3, a1);              // taps 0..61, zero memory ops

  // ---- stores: 64 lanes x 4B contiguous per row; planes: 0=s1, 1=s3, 2=s6
  const int srow = s0 + RPT * ty;
  float* o1 = out + (((size_t)b * 3 + 0) * S_LEN + srow) * NCH + c;
  float* o3 = out + (((size_t)b * 3 + 1) * S_LEN + srow) * NCH + c;
  float* o6 = out + (((size_t)b * 3 + 2) * S_LEN + srow) * NCH + c;
  Store<0>::run(o1, o3, o6, a6, a3, a1);
}

extern "C" void kernel_launch(void* const* d_in, const int* in_sizes, int n_in,
                              void* d_out, int out_size, void* d_ws, size_t ws_size,
                              hipStream_t stream) {
  (void)n_in; (void)out_size; (void)d_ws; (void)ws_size;
  const float* x = (const float*)d_in[0];
  float* out = (float*)d_out;
  const int B = in_sizes[0] / (S_LEN * NCH);   // 32

  const int nblk = (S_LEN / TILE_S) * B;       // 64 * 32 = 2048 (div by 8)
  dim3 grid(nblk);
  dim3 block(NCH, TY);                         // 512 threads = 8 waves
  hipLaunchKernelGGL(cwt_main, grid, block, 0, stream, x, out);
}